// Round 12
// baseline (253.241 us; speedup 1.0000x reference)
//
#include <hip/hip_runtime.h>
#include <hip/hip_bf16.h>

typedef _Float16 h8 __attribute__((ext_vector_type(8)));
typedef float f4 __attribute__((ext_vector_type(4)));

#define N_TOK 65536
#define DIM 256
#define KCODES 1024
#define HWSZ 4096

// async global->LDS, 16B per lane. LDS dest = wave-uniform base + lane*16.
__device__ __forceinline__ void gll16(const void* g, void* l) {
    __builtin_amdgcn_global_load_lds((const __attribute__((address_space(1))) void*)g,
                                     (__attribute__((address_space(3))) void*)l, 16, 0, 0);
}

// Fragment layout (A and B operands, 16x16x32 f16 MFMA):
//   element (n, d) -> granule G = ((n>>4)*8 + (d>>5))*64 + ((d>>3)&3)*16 + (n&15),
//   half j = d&7 inside the 16B granule. Conflict-free ds_read_b128, linear gll16.

// ---------------- K0a: embedding -> fragment-layout fp16 hi/lo ---------------
__global__ void k_prep_frag(const float* __restrict__ emb, _Float16* __restrict__ BhF,
                            _Float16* __restrict__ BlF) {
    int gi = blockIdx.x * 256 + threadIdx.x;
    int kb = gi >> 9, s = (gi >> 6) & 7, dq = (gi >> 4) & 3, r = gi & 15;
    int code = kb * 16 + r;
    const float* src = emb + (size_t)code * DIM + s * 32 + dq * 8;
    float4 x0 = *(const float4*)(src);
    float4 x1 = *(const float4*)(src + 4);
    float xs[8] = {x0.x, x0.y, x0.z, x0.w, x1.x, x1.y, x1.z, x1.w};
    h8 hi, lo;
#pragma unroll
    for (int j = 0; j < 8; ++j) {
        _Float16 h = (_Float16)xs[j];
        hi[j] = h;
        lo[j] = (_Float16)(xs[j] - (float)h);
    }
    *(h8*)(BhF + (size_t)gi * 8) = hi;
    *(h8*)(BlF + (size_t)gi * 8) = lo;
}

// ------------- K0b: e_sq + init the per-token atomic min-keys ----------------
__global__ void k_esq(const float* __restrict__ emb, float* __restrict__ e_sq,
                      unsigned long long* __restrict__ key64) {
    int t = threadIdx.x;
    key64[blockIdx.x * 256 + t] = ~0ull;   // grid 256x256 == N_TOK exactly
    int code = blockIdx.x * 4 + (t >> 6);
    int l = t & 63;
    float4 v = *(const float4*)(emb + (size_t)code * DIM + l * 4);
    float s = v.x * v.x + v.y * v.y + v.z * v.z + v.w * v.w;
#pragma unroll
    for (int off = 32; off >= 1; off >>= 1) s += __shfl_xor(s, off);
    if (l == 0) e_sq[code] = s;
}

// ------- K1: transpose z[B,C,H,W] -> enc[N,C] + fragment fp16 hi/lo ----------
__global__ void k_transpose(const float* __restrict__ z, float* __restrict__ enc,
                            _Float16* __restrict__ AhF, _Float16* __restrict__ AlF) {
    __shared__ float T[64][65];
    int blk = blockIdx.x;
    int b = blk >> 8;
    int rem = blk & 255;
    int c0 = (rem >> 6) * 64;
    int hw0 = (rem & 63) * 64;
    int t = threadIdx.x;
    const float* zp = z + (size_t)b * DIM * HWSZ;
    {
        int hw4 = (t & 15) * 4, cl = t >> 4;
#pragma unroll
        for (int i = 0; i < 4; ++i) {
            int c = cl + i * 16;
            float4 v = *(const float4*)(zp + (size_t)(c0 + c) * HWSZ + hw0 + hw4);
            T[c][hw4 + 0] = v.x; T[c][hw4 + 1] = v.y;
            T[c][hw4 + 2] = v.z; T[c][hw4 + 3] = v.w;
        }
    }
    __syncthreads();
    {
        int c4 = (t & 15) * 4, hwl = t >> 4;
#pragma unroll
        for (int i = 0; i < 4; ++i) {
            int hw = hwl + i * 16;
            float4 v;
            v.x = T[c4 + 0][hw]; v.y = T[c4 + 1][hw];
            v.z = T[c4 + 2][hw]; v.w = T[c4 + 3][hw];
            *(float4*)(enc + (size_t)(b * HWSZ + hw0 + hw) * DIM + c0 + c4) = v;
        }
    }
    {
        int base_nb = b * 256 + (hw0 >> 4);
#pragma unroll
        for (int i = 0; i < 2; ++i) {
            int gidx = i * 256 + t;
            int nbi = gidx >> 7, si = (gidx >> 6) & 1, dq = (gidx >> 4) & 3, r = gidx & 15;
            int hwl = nbi * 16 + r;
            int cl = si * 32 + dq * 8;
            h8 hi, lo;
#pragma unroll
            for (int j = 0; j < 8; ++j) {
                float x = T[cl + j][hwl];
                _Float16 h = (_Float16)x;
                hi[j] = h;
                lo[j] = (_Float16)(x - (float)h);
            }
            size_t G = (((size_t)(base_nb + nbi) * 8) + (c0 >> 5) + si) * 64 + dq * 16 + r;
            *(h8*)(AhF + G * 8) = hi;
            *(h8*)(AlF + G * 8) = lo;
        }
    }
}

// ---- K2: GEMM (fp16 split, 3 passes), 128x128 tile, 2 blocks/CU -------------
#define WAITV(n) asm volatile("s_waitcnt vmcnt(" #n ")" ::: "memory")
#define BARRIER __builtin_amdgcn_s_barrier()
#define PRIO1 __builtin_amdgcn_s_setprio(1)
#define PRIO0 __builtin_amdgcn_s_setprio(0)

extern __shared__ char SB[];   // 2 step-bufs x 32 KB: [Ah 8K][Bh 8K][Al 8K][Bl 8K]

__global__ __launch_bounds__(512, 4)
void k_gemm_argmin(const _Float16* __restrict__ AhF, const _Float16* __restrict__ AlF,
                   const _Float16* __restrict__ BhF, const _Float16* __restrict__ BlF,
                   const float* __restrict__ e_sq,
                   unsigned long long* __restrict__ key64) {
    int gid = blockIdx.x;
    // rchunk-major: 8-MB A chunks (64 rowTiles of 128) reused across 8 colTiles
    int grp = gid >> 9;
    int colTile = (gid >> 6) & 7;
    int rowTile = grp * 64 + (gid & 63);
    int r0 = rowTile * 128, c0 = colTile * 128;
    int t = threadIdx.x;
    int w = t >> 6, l = t & 63;           // 8 waves
    int wm = w >> 2, wn = w & 3;          // wave tile 64 rows x 32 cols
    int l16 = l & 15, lhi = l >> 4;

    const char* gAh = (const char*)AhF + (((size_t)(rowTile * 8 + w)) << 13) + (l << 4);
    const char* gAl = (const char*)AlF + (((size_t)(rowTile * 8 + w)) << 13) + (l << 4);
    const char* gBh = (const char*)BhF + (((size_t)(colTile * 8 + w)) << 13) + (l << 4);
    const char* gBl = (const char*)BlF + (((size_t)(colTile * 8 + w)) << 13) + (l << 4);

// stage all 4 operand chunks of K-step s into ring buf s&1 (4 KB per wave)
#define ISSUE_S(s) do { \
    char* bp_ = SB + ((s) & 1) * 32768; \
    gll16(gAh + ((s) << 10), bp_ + (w << 10)); \
    gll16(gBh + ((s) << 10), bp_ + 8192 + (w << 10)); \
    gll16(gAl + ((s) << 10), bp_ + 16384 + (w << 10)); \
    gll16(gBl + ((s) << 10), bp_ + 24576 + (w << 10)); \
} while (0)

#define MFMA8(A_, B_) { _Pragma("unroll") for (int mf = 0; mf < 4; ++mf) \
    _Pragma("unroll") for (int nf = 0; nf < 2; ++nf) \
        acc[mf][nf] = __builtin_amdgcn_mfma_f32_16x16x32_f16(A_[mf], B_[nf], acc[mf][nf], 0, 0, 0); }

// one K-step: hh burst, then (bl read + hl burst), then (al read + lh burst)
#define PHASE(q, DO_ISSUE) { \
    WAITV(0); \
    BARRIER; \
    if (DO_ISSUE) ISSUE_S((q) + 1); \
    const char* bp_ = SB + ((q) & 1) * 32768; \
    _Pragma("unroll") for (int mf = 0; mf < 4; ++mf) \
        ah[mf] = *(const h8*)(bp_ + ((wm * 4 + mf) << 10) + (l << 4)); \
    _Pragma("unroll") for (int nf = 0; nf < 2; ++nf) \
        bh[nf] = *(const h8*)(bp_ + 8192 + ((wn * 2 + nf) << 10) + (l << 4)); \
    PRIO1; MFMA8(ah, bh); PRIO0; \
    { h8 xb[2]; \
      _Pragma("unroll") for (int nf = 0; nf < 2; ++nf) \
          xb[nf] = *(const h8*)(bp_ + 24576 + ((wn * 2 + nf) << 10) + (l << 4)); \
      PRIO1; MFMA8(ah, xb); PRIO0; } \
    { h8 xa[4]; \
      _Pragma("unroll") for (int mf = 0; mf < 4; ++mf) \
          xa[mf] = *(const h8*)(bp_ + 16384 + ((wm * 4 + mf) << 10) + (l << 4)); \
      PRIO1; MFMA8(xa, bh); PRIO0; } }

    f4 acc[4][2];
#pragma unroll
    for (int i = 0; i < 4; ++i)
#pragma unroll
        for (int j = 0; j < 2; ++j) acc[i][j] = (f4)0.0f;

    h8 ah[4], bh[2];

    ISSUE_S(0);   // prologue: step 0 in flight

    PHASE(0, 1)  PHASE(1, 1)  PHASE(2, 1)  PHASE(3, 1)
    PHASE(4, 1)  PHASE(5, 1)  PHASE(6, 1)  PHASE(7, 0)

    // ---- per-row argmin over this block's 128 codes ----
    // scratch overlays ring buf 0 Ah region (phase 7 computed from buf 1)
    float* smV = (float*)SB;          // [4][128]
    int* smI = (int*)(SB + 2048);     // [4][128]

    float esq[2];
#pragma unroll
    for (int nf = 0; nf < 2; ++nf) esq[nf] = e_sq[c0 + wn * 32 + nf * 16 + l16];

#pragma unroll
    for (int mf = 0; mf < 4; ++mf) {
#pragma unroll
        for (int rg = 0; rg < 4; ++rg) {
            float bestV = 3.4e38f;
            int bestI = 0;
#pragma unroll
            for (int nf = 0; nf < 2; ++nf) {
                float v = esq[nf] - 2.0f * acc[mf][nf][rg];
                int ci = c0 + wn * 32 + nf * 16 + l16;
                if (v < bestV || (v == bestV && ci < bestI)) { bestV = v; bestI = ci; }
            }
#pragma unroll
            for (int off = 1; off < 16; off <<= 1) {
                float vv = __shfl_xor(bestV, off);
                int ii = __shfl_xor(bestI, off);
                if (vv < bestV || (vv == bestV && ii < bestI)) { bestV = vv; bestI = ii; }
            }
            if (l16 == 0) {
                int rloc = wm * 64 + mf * 16 + lhi * 4 + rg;
                smV[wn * 128 + rloc] = bestV;
                smI[wn * 128 + rloc] = bestI;
            }
        }
    }
    __syncthreads();
    if (t < 128) {
        float bestV = smV[t];
        int bestI = smI[t];
#pragma unroll
        for (int wn2 = 1; wn2 < 4; ++wn2) {
            float v = smV[wn2 * 128 + t];
            int i2 = smI[wn2 * 128 + t];
            if (v < bestV || (v == bestV && i2 < bestI)) { bestV = v; bestI = i2; }
        }
        // order-preserving encode: min key == (min value, then min index)
        unsigned int bu = __float_as_uint(bestV);
        unsigned int u = (bu & 0x80000000u) ? ~bu : (bu | 0x80000000u);
        unsigned long long key = ((unsigned long long)u << 10) | (unsigned int)bestI;
        atomicMin(&key64[r0 + t], key);
    }
}

// ---- K3: fused epilogue: decode keys -> out2, gather out1, transpose out3 ---
__global__ void k_final_all(const unsigned long long* __restrict__ key64,
                            const float* __restrict__ emb,
                            float* __restrict__ out2, float* __restrict__ out1,
                            float* __restrict__ out3) {
    __shared__ int sidx[64];
    __shared__ float E[32][257];
    int t = threadIdx.x;
    int n0 = blockIdx.x * 64;
    if (t < 64) {
        int idx = (int)(key64[n0 + t] & 1023ull);
        out2[n0 + t] = (float)idx;
        sidx[t] = idx;
    }
    __syncthreads();
    // out1: gather embedding rows (64 rows, 4 threads/row)
    {
        int r = t >> 2, q = t & 3;
        int idx = sidx[r];
        const float* src = emb + (size_t)idx * DIM + q * 64;
        float* dst = out1 + (size_t)(n0 + r) * DIM + q * 64;
#pragma unroll
        for (int j = 0; j < 16; ++j)
            *(float4*)(dst + j * 4) = *(const float4*)(src + j * 4);
    }
    // out3: transposed writes, 2 sub-chunks of 32 tokens
    int b = n0 >> 12;
    int hw0b = n0 & 4095;
    for (int sub = 0; sub < 2; ++sub) {
        __syncthreads();
        {
            int r = t >> 3, oct = t & 7;
            int idx = sidx[sub * 32 + r];
            const float* src = emb + (size_t)idx * DIM + oct * 32;
#pragma unroll
            for (int i = 0; i < 8; ++i) {
                float4 v = *(const float4*)(src + i * 4);
                E[r][oct * 32 + i * 4 + 0] = v.x;
                E[r][oct * 32 + i * 4 + 1] = v.y;
                E[r][oct * 32 + i * 4 + 2] = v.z;
                E[r][oct * 32 + i * 4 + 3] = v.w;
            }
        }
        __syncthreads();
        {
            int w = t >> 6, l = t & 63;
            int ch = l >> 5, hw = l & 31;
            float* dst = out3 + (size_t)b * DIM * HWSZ + hw0b + sub * 32 + hw;
#pragma unroll
            for (int it = 0; it < 32; ++it) {
                int c = w * 64 + it * 2 + ch;
                dst[(size_t)c * HWSZ] = E[hw][c];
            }
        }
    }
}

extern "C" void kernel_launch(void* const* d_in, const int* in_sizes, int n_in,
                              void* d_out, int out_size, void* d_ws, size_t ws_size,
                              hipStream_t stream) {
    const float* z = (const float*)d_in[0];
    const float* emb = (const float*)d_in[1];
    float* out = (float*)d_out;
    float* out0 = out;                    // encoded_flat  [65536,256]
    float* out1 = out + 16777216;         // quantized_flat[65536,256]
    float* out2 = out + 33554432;         // indices       [65536] (as float)
    float* out3 = out + 33619968;         // quantized     [16,256,64,64]

    // A-operand fp16 hi/lo scratch fills the out1 region (64 MB); out1 is
    // written afterwards by k_final_all.
    _Float16* AhF = (_Float16*)out1;
    _Float16* AlF = (_Float16*)(out1 + 8388608);

    char* ws = (char*)d_ws;
    _Float16* BhF = (_Float16*)(ws);                          // 512 KB
    _Float16* BlF = (_Float16*)(ws + 524288);                 // 512 KB
    float* e_sq = (float*)(ws + 1048576);                     // 4 KB
    unsigned long long* key64 = (unsigned long long*)(ws + 1052672);  // 512 KB

    hipFuncSetAttribute((const void*)k_gemm_argmin,
                        hipFuncAttributeMaxDynamicSharedMemorySize, 65536);

    k_prep_frag<<<128, 256, 0, stream>>>(emb, BhF, BlF);
    k_esq<<<256, 256, 0, stream>>>(emb, e_sq, key64);
    k_transpose<<<4096, 256, 0, stream>>>(z, out0, AhF, AlF);
    k_gemm_argmin<<<4096, 512, 65536, stream>>>(AhF, AlF, BhF, BlF, e_sq, key64);
    k_final_all<<<1024, 256, 0, stream>>>(key64, emb, out2, out1, out3);
}

// Round 13
// 222.264 us; speedup vs baseline: 1.1394x; 1.1394x over previous
//
#include <hip/hip_runtime.h>
#include <hip/hip_bf16.h>

typedef _Float16 h8 __attribute__((ext_vector_type(8)));
typedef float f4 __attribute__((ext_vector_type(4)));

#define N_TOK 65536
#define DIM 256
#define KCODES 1024
#define HWSZ 4096

// async global->LDS, 16B per lane. LDS dest = wave-uniform base + lane*16.
__device__ __forceinline__ void gll16(const void* g, void* l) {
    __builtin_amdgcn_global_load_lds((const __attribute__((address_space(1))) void*)g,
                                     (__attribute__((address_space(3))) void*)l, 16, 0, 0);
}

// Fragment layout (A and B operands, 16x16x32 f16 MFMA):
//   element (n, d) -> granule G = ((n>>4)*8 + (d>>5))*64 + ((d>>3)&3)*16 + (n&15),
//   half j = d&7 inside the 16B granule. Conflict-free ds_read_b128, linear gll16.

// ---------------- K0a: embedding -> fragment-layout fp16 hi/lo ---------------
__global__ void k_prep_frag(const float* __restrict__ emb, _Float16* __restrict__ BhF,
                            _Float16* __restrict__ BlF) {
    int gi = blockIdx.x * 256 + threadIdx.x;
    int kb = gi >> 9, s = (gi >> 6) & 7, dq = (gi >> 4) & 3, r = gi & 15;
    int code = kb * 16 + r;
    const float* src = emb + (size_t)code * DIM + s * 32 + dq * 8;
    float4 x0 = *(const float4*)(src);
    float4 x1 = *(const float4*)(src + 4);
    float xs[8] = {x0.x, x0.y, x0.z, x0.w, x1.x, x1.y, x1.z, x1.w};
    h8 hi, lo;
#pragma unroll
    for (int j = 0; j < 8; ++j) {
        _Float16 h = (_Float16)xs[j];
        hi[j] = h;
        lo[j] = (_Float16)(xs[j] - (float)h);
    }
    *(h8*)(BhF + (size_t)gi * 8) = hi;
    *(h8*)(BlF + (size_t)gi * 8) = lo;
}

// ---------------- K0b: e_sq ---------------------------------------------------
__global__ void k_esq(const float* __restrict__ emb, float* __restrict__ e_sq) {
    int t = threadIdx.x;
    int code = blockIdx.x * 4 + (t >> 6);
    int l = t & 63;
    float4 v = *(const float4*)(emb + (size_t)code * DIM + l * 4);
    float s = v.x * v.x + v.y * v.y + v.z * v.z + v.w * v.w;
#pragma unroll
    for (int off = 32; off >= 1; off >>= 1) s += __shfl_xor(s, off);
    if (l == 0) e_sq[code] = s;
}

// ------- K1: transpose z[B,C,H,W] -> enc[N,C] + fragment fp16 hi/lo ----------
__global__ void k_transpose(const float* __restrict__ z, float* __restrict__ enc,
                            _Float16* __restrict__ AhF, _Float16* __restrict__ AlF) {
    __shared__ float T[64][65];
    int blk = blockIdx.x;
    int b = blk >> 8;
    int rem = blk & 255;
    int c0 = (rem >> 6) * 64;
    int hw0 = (rem & 63) * 64;
    int t = threadIdx.x;
    const float* zp = z + (size_t)b * DIM * HWSZ;
    {
        int hw4 = (t & 15) * 4, cl = t >> 4;
#pragma unroll
        for (int i = 0; i < 4; ++i) {
            int c = cl + i * 16;
            float4 v = *(const float4*)(zp + (size_t)(c0 + c) * HWSZ + hw0 + hw4);
            T[c][hw4 + 0] = v.x; T[c][hw4 + 1] = v.y;
            T[c][hw4 + 2] = v.z; T[c][hw4 + 3] = v.w;
        }
    }
    __syncthreads();
    {
        int c4 = (t & 15) * 4, hwl = t >> 4;
#pragma unroll
        for (int i = 0; i < 4; ++i) {
            int hw = hwl + i * 16;
            float4 v;
            v.x = T[c4 + 0][hw]; v.y = T[c4 + 1][hw];
            v.z = T[c4 + 2][hw]; v.w = T[c4 + 3][hw];
            *(float4*)(enc + (size_t)(b * HWSZ + hw0 + hw) * DIM + c0 + c4) = v;
        }
    }
    {
        int base_nb = b * 256 + (hw0 >> 4);
#pragma unroll
        for (int i = 0; i < 2; ++i) {
            int gidx = i * 256 + t;
            int nbi = gidx >> 7, si = (gidx >> 6) & 1, dq = (gidx >> 4) & 3, r = gidx & 15;
            int hwl = nbi * 16 + r;
            int cl = si * 32 + dq * 8;
            h8 hi, lo;
#pragma unroll
            for (int j = 0; j < 8; ++j) {
                float x = T[cl + j][hwl];
                _Float16 h = (_Float16)x;
                hi[j] = h;
                lo[j] = (_Float16)(x - (float)h);
            }
            size_t G = (((size_t)(base_nb + nbi) * 8) + (c0 >> 5) + si) * 64 + dq * 16 + r;
            *(h8*)(AhF + G * 8) = hi;
            *(h8*)(AlF + G * 8) = lo;
        }
    }
}

// ---- K2: GEMM, 8-phase-style schedule over virtual K=768 (24 K32 chunks) ----
// chunk c: pass p=c>>3 (0:hh 1:hl 2:lh), d-step s=c&7. Uniform compute; only
// staging source differs per pass. 4 LDS chunk-bufs x 32 KB = 128 KB.
#define WAITV(n) asm volatile("s_waitcnt vmcnt(" #n ")" ::: "memory")
#define BARRIER __builtin_amdgcn_s_barrier()
#define PRIO1 __builtin_amdgcn_s_setprio(1)
#define PRIO0 __builtin_amdgcn_s_setprio(0)
#define LGKM0 asm volatile("s_waitcnt lgkmcnt(0)" ::: "memory")
#define SGB0 __builtin_amdgcn_sched_barrier(0)

extern __shared__ char SB[];

__global__ __launch_bounds__(512, 2)
void k_gemm_argmin(const _Float16* __restrict__ AhF, const _Float16* __restrict__ AlF,
                   const _Float16* __restrict__ BhF, const _Float16* __restrict__ BlF,
                   const float* __restrict__ e_sq,
                   float* __restrict__ pV1, int* __restrict__ pI1) {
    int gid = blockIdx.x;
    // rchunk-major: 8-MB A chunks (32 rowTiles) reused across all 4 colTiles
    int grp = gid >> 7;
    int colTile = (gid >> 5) & 3;
    int rowTile = grp * 32 + (gid & 31);
    int r0 = rowTile * 256, c0 = colTile * 256;
    int t = threadIdx.x;
    int w = t >> 6, l = t & 63;           // 8 waves
    int wm = w >> 2, wn = w & 3;          // wave tile 128 rows x 64 cols
    int l16 = l & 15, lhi = l >> 4;

    // staging: wave w owns nb-blocks {2w, 2w+1} of A (rows) and of B (cols)
    const char* gAh = (const char*)AhF + (((size_t)(rowTile * 16 + 2 * w)) << 13) + (l << 4);
    const char* gAl = (const char*)AlF + (((size_t)(rowTile * 16 + 2 * w)) << 13) + (l << 4);
    const char* gBh = (const char*)BhF + (((size_t)(colTile * 16 + 2 * w)) << 13) + (l << 4);
    const char* gBl = (const char*)BlF + (((size_t)(colTile * 16 + 2 * w)) << 13) + (l << 4);

#define ISSUE_A(c) do { const char* a_ = (((c) >> 3) == 2) ? gAl : gAh; \
    char* bp_ = SB + ((c) & 3) * 32768 + ((2 * w) << 10); \
    const int so_ = ((c) & 7) << 10; \
    gll16(a_ + so_, bp_); gll16(a_ + 8192 + so_, bp_ + 1024); } while (0)

#define ISSUE_B(c) do { const char* b_ = (((c) >> 3) == 1) ? gBl : gBh; \
    char* bp_ = SB + ((c) & 3) * 32768 + 16384 + ((2 * w) << 10); \
    const int so_ = ((c) & 7) << 10; \
    gll16(b_ + so_, bp_); gll16(b_ + 8192 + so_, bp_ + 1024); } while (0)

#define RD_A(c, mo) { const char* bp_ = SB + ((c) & 3) * 32768; \
    _Pragma("unroll") for (int mf = 0; mf < 4; ++mf) \
        ah[mf] = *(const h8*)(bp_ + ((wm * 8 + (mo) + mf) << 10) + (l << 4)); }

#define RD_B(c) { const char* bp_ = SB + ((c) & 3) * 32768 + 16384; \
    _Pragma("unroll") for (int nf = 0; nf < 4; ++nf) \
        bh[nf] = *(const h8*)(bp_ + ((wn * 4 + nf) << 10) + (l << 4)); }

#define MFMA_HALF(mo) { _Pragma("unroll") for (int mf = 0; mf < 4; ++mf) \
    _Pragma("unroll") for (int nf = 0; nf < 4; ++nf) \
        acc[(mo) + mf][nf] = __builtin_amdgcn_mfma_f32_16x16x32_f16(ah[mf], bh[nf], acc[(mo) + mf][nf], 0, 0, 0); }

// one chunk = 2 phases. Phase: barrier -> issue stage (c+3) -> ds_read ->
// lgkmcnt(0)+sched_barrier -> setprio MFMA cluster (16). vmcnt counted (8),
// never 0 until the 3-chunk tail.
#define CHUNK(c, W) \
    WAITV(W); BARRIER; \
    if ((c) <= 20) { ISSUE_A((c) + 3); } \
    RD_A(c, 0); RD_B(c); \
    LGKM0; SGB0; PRIO1; MFMA_HALF(0); PRIO0; \
    BARRIER; \
    if ((c) <= 20) { ISSUE_B((c) + 3); } \
    RD_A(c, 4); \
    LGKM0; SGB0; PRIO1; MFMA_HALF(4); PRIO0;

    f4 acc[8][4];
#pragma unroll
    for (int i = 0; i < 8; ++i)
#pragma unroll
        for (int j = 0; j < 4; ++j) acc[i][j] = (f4)0.0f;

    h8 ah[4], bh[4];

    // prologue: chunks 0,1,2 in flight (12 loads per wave)
    ISSUE_A(0); ISSUE_B(0); ISSUE_A(1); ISSUE_B(1); ISSUE_A(2); ISSUE_B(2);

    CHUNK(0, 8)   CHUNK(1, 8)   CHUNK(2, 8)   CHUNK(3, 8)
    CHUNK(4, 8)   CHUNK(5, 8)   CHUNK(6, 8)   CHUNK(7, 8)
    CHUNK(8, 8)   CHUNK(9, 8)   CHUNK(10, 8)  CHUNK(11, 8)
    CHUNK(12, 8)  CHUNK(13, 8)  CHUNK(14, 8)  CHUNK(15, 8)
    CHUNK(16, 8)  CHUNK(17, 8)  CHUNK(18, 8)  CHUNK(19, 8)
    CHUNK(20, 8)  CHUNK(21, 8)  CHUNK(22, 4)  CHUNK(23, 0)

    // ---- scores + per-row argmin over this block's 256 codes ----
    // scratch overlays buf0 A-region (chunk 23 used buf3)
    float* smV = (float*)SB;          // [4][256]
    int* smI = (int*)(SB + 4096);     // [4][256]

    float esq[4];
#pragma unroll
    for (int nf = 0; nf < 4; ++nf) esq[nf] = e_sq[c0 + wn * 64 + nf * 16 + l16];

#pragma unroll
    for (int mf = 0; mf < 8; ++mf) {
#pragma unroll
        for (int rg = 0; rg < 4; ++rg) {
            float bestV = 3.4e38f;
            int bestI = 0;
#pragma unroll
            for (int nf = 0; nf < 4; ++nf) {
                float v = esq[nf] - 2.0f * acc[mf][nf][rg];
                int ci = c0 + wn * 64 + nf * 16 + l16;
                if (v < bestV || (v == bestV && ci < bestI)) { bestV = v; bestI = ci; }
            }
#pragma unroll
            for (int off = 1; off < 16; off <<= 1) {
                float vv = __shfl_xor(bestV, off);
                int ii = __shfl_xor(bestI, off);
                if (vv < bestV || (vv == bestV && ii < bestI)) { bestV = vv; bestI = ii; }
            }
            if (l16 == 0) {
                int rloc = wm * 128 + mf * 16 + lhi * 4 + rg;
                smV[wn * 256 + rloc] = bestV;
                smI[wn * 256 + rloc] = bestI;
            }
        }
    }
    __syncthreads();
    if (t < 256) {
        float bestV = smV[t];
        int bestI = smI[t];
#pragma unroll
        for (int wn2 = 1; wn2 < 4; ++wn2) {
            float v = smV[wn2 * 256 + t];
            int i2 = smI[wn2 * 256 + t];
            if (v < bestV || (v == bestV && i2 < bestI)) { bestV = v; bestI = i2; }
        }
        pV1[colTile * N_TOK + r0 + t] = bestV;
        pI1[colTile * N_TOK + r0 + t] = bestI;
    }
}

// ---- K3: fused epilogue: combine -> out2, gather out1, transpose out3 -------
__global__ void k_final_all(const float* __restrict__ pV1, const int* __restrict__ pI1,
                            const float* __restrict__ emb,
                            float* __restrict__ out2, float* __restrict__ out1,
                            float* __restrict__ out3) {
    __shared__ int sidx[256];
    __shared__ float E[32][257];
    int t = threadIdx.x;
    int n0 = blockIdx.x * 256;
    int n = n0 + t;
    float v1 = pV1[n];
    int i1 = pI1[n];
#pragma unroll
    for (int ct = 1; ct < 4; ++ct) {
        float a1 = pV1[ct * N_TOK + n];
        int ai = pI1[ct * N_TOK + n];
        if (a1 < v1 || (a1 == v1 && ai < i1)) { v1 = a1; i1 = ai; }
    }
    out2[n] = (float)i1;
    sidx[t] = i1;
    __syncthreads();
    {
        int rr = t >> 2, q = t & 3;
#pragma unroll
        for (int i = 0; i < 4; ++i) {
            int r = i * 64 + rr;
            int idx = sidx[r];
            const float* src = emb + (size_t)idx * DIM + q * 64;
            float* dst = out1 + (size_t)(n0 + r) * DIM + q * 64;
#pragma unroll
            for (int j = 0; j < 16; ++j)
                *(float4*)(dst + j * 4) = *(const float4*)(src + j * 4);
        }
    }
    int b = n0 >> 12;
    int hw0b = n0 & 4095;
    for (int sub = 0; sub < 8; ++sub) {
        __syncthreads();
        {
            int r = t >> 3, oct = t & 7;
            int idx = sidx[sub * 32 + r];
            const float* src = emb + (size_t)idx * DIM + oct * 32;
#pragma unroll
            for (int i = 0; i < 8; ++i) {
                float4 v = *(const float4*)(src + i * 4);
                E[r][oct * 32 + i * 4 + 0] = v.x;
                E[r][oct * 32 + i * 4 + 1] = v.y;
                E[r][oct * 32 + i * 4 + 2] = v.z;
                E[r][oct * 32 + i * 4 + 3] = v.w;
            }
        }
        __syncthreads();
        {
            int w = t >> 6, l = t & 63;
            int ch = l >> 5, hw = l & 31;
            float* dst = out3 + (size_t)b * DIM * HWSZ + hw0b + sub * 32 + hw;
#pragma unroll
            for (int it = 0; it < 32; ++it) {
                int c = w * 64 + it * 2 + ch;
                dst[(size_t)c * HWSZ] = E[hw][c];
            }
        }
    }
}

extern "C" void kernel_launch(void* const* d_in, const int* in_sizes, int n_in,
                              void* d_out, int out_size, void* d_ws, size_t ws_size,
                              hipStream_t stream) {
    const float* z = (const float*)d_in[0];
    const float* emb = (const float*)d_in[1];
    float* out = (float*)d_out;
    float* out0 = out;                    // encoded_flat  [65536,256]
    float* out1 = out + 16777216;         // quantized_flat[65536,256]
    float* out2 = out + 33554432;         // indices       [65536] (as float)
    float* out3 = out + 33619968;         // quantized     [16,256,64,64]

    // A-operand fp16 hi/lo scratch fills the out1 region (64 MB); out1 is
    // written afterwards by k_final_all.
    _Float16* AhF = (_Float16*)out1;
    _Float16* AlF = (_Float16*)(out1 + 8388608);

    char* ws = (char*)d_ws;
    _Float16* BhF = (_Float16*)(ws);                 // 512 KB
    _Float16* BlF = (_Float16*)(ws + 524288);        // 512 KB
    float* e_sq = (float*)(ws + 1048576);            // 4 KB
    float* pV1 = (float*)(ws + 1052672);             // 1 MB
    int* pI1 = (int*)(ws + 2101248);                 // 1 MB

    hipFuncSetAttribute((const void*)k_gemm_argmin,
                        hipFuncAttributeMaxDynamicSharedMemorySize, 131072);

    k_prep_frag<<<128, 256, 0, stream>>>(emb, BhF, BlF);
    k_esq<<<256, 256, 0, stream>>>(emb, e_sq);
    k_transpose<<<4096, 256, 0, stream>>>(z, out0, AhF, AlF);
    k_gemm_argmin<<<1024, 512, 131072, stream>>>(AhF, AlF, BhF, BlF, e_sq, pV1, pI1);
    k_final_all<<<256, 256, 0, stream>>>(pV1, pI1, emb, out2, out1, out3);
}